// Round 6
// baseline (235.331 us; speedup 1.0000x reference)
//
#include <hip/hip_runtime.h>
#include <stdint.h>

#define IN_C   128
#define OUT_C  128
#define KTOT   1152      // IN_C*3*3
#define NG     8
#define NW     8
#define NB     8
#define HH     56
#define WWID   56
#define NPIX   3136
#define PPAD   3200
#define MTOT   1024      // OUT_C*NW
#define HALO   58        // 56 + zero border on each side
#define HPIX   (HALO*HALO)   // 3364

// R6: BARRIER-FREE register-resident GEMM. The LDS round-trip for B was
// recomputable as a direct global load: lane (lq,lr) of tile (nt,tn) needs
// exactly Xt[(y*58+x)*128 + c0 + lq*8 ..+8] (16B contiguous). So both A and B
// fragments load global->VGPR (SGPR base + per-lane 32b offset + scalar stage
// offset). Deletes all cp16 / __syncthreads / ds_read / bank conflicts -- the
// serialized LDS+barrier path that R3/R4 showed to be occupancy- and
// latency-invariant (~181k cy/CU = MFMA 68k + ds_read 84k + conflicts 29k).
// Ping-pong reload-after-consume gives natural counted-vmcnt (8 in flight).
// NO launch_bounds register cap (R2/R5 lesson: cap -> scratch spills).

typedef __attribute__((ext_vector_type(8))) short short8;
typedef __attribute__((ext_vector_type(8))) unsigned short ushort8;
typedef __attribute__((ext_vector_type(4))) float f32x4;

__device__ __forceinline__ unsigned short f2bf(float f) {
    unsigned u = __float_as_uint(f);
    u += 0x7FFF + ((u >> 16) & 1);          // round-to-nearest-even
    return (unsigned short)(u >> 16);
}

__device__ __forceinline__ void cp16(const unsigned short* g, unsigned short* l) {
    __builtin_amdgcn_global_load_lds(
        (const __attribute__((address_space(1))) unsigned int*)g,
        (__attribute__((address_space(3))) unsigned int*)l,
        16, 0, 0);
}

// ---------- 1) fused prep: gap (0..1023) | tconv/pack (1024..1151) | transpose (1152..1375) ----------
__global__ __launch_bounds__(256) void prep_kernel(const float* __restrict__ in,
                                                   const float* __restrict__ T,
                                                   float* __restrict__ xse,
                                                   unsigned short* __restrict__ Apack,
                                                   unsigned short* __restrict__ Xt) {
    __shared__ __align__(16) unsigned char smem[32768];   // 32 KB
    const int blk = blockIdx.x;
    const int t = threadIdx.x;

    if (blk < 1024) {
        // ---- global average pool: xse[b,c] ----
        const float* src = in + (size_t)blk * NPIX;
        float s = 0.f;
        for (int i = t; i < NPIX / 4; i += 256) {
            float4 v = ((const float4*)src)[i];
            s += v.x + v.y + v.z + v.w;
        }
        #pragma unroll
        for (int off = 32; off; off >>= 1) s += __shfl_down(s, off);
        float* ws4 = (float*)smem;
        if ((t & 63) == 0) ws4[t >> 6] = s;
        __syncthreads();
        if (t == 0)
            xse[blk] = (ws4[0] + ws4[1] + ws4[2] + ws4[3]) * (1.0f / (float)NPIX);
        return;
    }
    if (blk < 1152) {
        // ---- tconv+pack: block per o. T[o][k][j] slab -> bf16 LDS (18 KB) ->
        //      fragment-linear Apack[m16][kt][lq][lr][8e].
        unsigned short* lh = (unsigned short*)smem;  // 9216 bf16 = 18 KB
        const int o = blk - 1024;
        const float* To = T + (size_t)o * 9216;
        #pragma unroll
        for (int it = 0; it < 9; it++) {
            const int f = it * 256 + t;              // 0..2303 float4 units
            const float4 v = ((const float4*)To)[f];
            ushort4 h;
            h.x = f2bf(v.x); h.y = f2bf(v.y); h.z = f2bf(v.z); h.w = f2bf(v.w);
            *(ushort4*)&lh[f * 4] = h;
        }
        __syncthreads();
        const int m16b = o >> 1;
        const int lrb = (o & 1) * 8;
        #pragma unroll
        for (int it = 0; it < 5; it++) {
            const int ch = it * 256 + t;             // 0..1151: ch = kc*8 + j
            if (ch < 1152) {
                const int j = ch & 7, kc = ch >> 3;  // kc = k-octet 0..143
                const int s = kc >> 4, c0 = (kc & 15) << 3;
                const int kt = kc >> 2, lq = kc & 3;
                ushort8 v;
                #pragma unroll
                for (int i = 0; i < 8; i++)
                    v[i] = lh[((c0 + i) * 9 + s) * 8 + j];
                const size_t off = ((((size_t)m16b * 36 + kt) * 4 + lq) * 16 + lrb + j) * 8;
                *(ushort8*)&Apack[off] = v;
            }
        }
        return;
    }
    // ---- transpose: in[b][c][y][x] fp32 -> Xt[b][(y+1)*58+(x+1)][c] bf16, zero halo ----
    unsigned short* tile = (unsigned short*)smem;    // 32 KB, [c][pix 0..112)
    const int idx = blk - 1152;                      // 0..223
    const int yt = idx % 28;
    const int b  = idx / 28;
    const int y0 = yt * 2;

    #pragma unroll
    for (int it = 0; it < 14; it++) {
        const int f = it * 256 + t;
        const int c = f / 28;
        const int rem = f - c * 28;
        const int y = rem / 14;
        const int x4 = rem - y * 14;
        const float4 v = *(const float4*)(in + ((size_t)(b * IN_C + c)) * NPIX
                                          + (y0 + y) * WWID + x4 * 4);
        unsigned short bf0 = f2bf(v.x), bf1 = f2bf(v.y), bf2 = f2bf(v.z), bf3 = f2bf(v.w);
        const int ppb = (y * WWID + x4 * 4) ^ (((c >> 3) & 15) << 2);
        uint2 pk;
        pk.x = (unsigned)bf0 | ((unsigned)bf1 << 16);
        pk.y = (unsigned)bf2 | ((unsigned)bf3 << 16);
        *(uint2*)&tile[c * 128 + ppb] = pk;
    }
    __syncthreads();

    #pragma unroll
    for (int it = 0; it < 7; it++) {
        const int ch = it * 256 + t;
        const int oct = ch & 15;
        const int pp = ch >> 4;
        const int sw = oct << 2;
        ushort8 v;
        #pragma unroll
        for (int i = 0; i < 8; i++)
            v[i] = tile[(oct * 8 + i) * 128 + (pp ^ sw)];
        const int y2 = (pp >= WWID) ? 1 : 0;
        const int xg = pp - y2 * WWID;
        const size_t hp = (size_t)b * HPIX + (y0 + y2 + 1) * HALO + (xg + 1);
        *(ushort8*)&Xt[hp * 128 + oct * 8] = v;
    }

    if (t < 64) {   // halo columns xx=0,57 for this block's two rows
        const int pi = t >> 4, oct = t & 15;
        const int yy = y0 + 1 + (pi >> 1);
        const int xx = (pi & 1) * 57;
        *(ushort8*)&Xt[((size_t)b * HPIX + yy * HALO + xx) * 128 + oct * 8] =
            (ushort8){0, 0, 0, 0, 0, 0, 0, 0};
    }
    if (yt == 0 || yt == 27) {   // halo rows yy=0 / 57
        const int yy = (yt == 0) ? 0 : 57;
        #pragma unroll
        for (int it = 0; it < 4; it++) {
            const int ch = it * 256 + t;
            if (ch < 928) {
                const int xx = ch >> 4, oct = ch & 15;
                *(ushort8*)&Xt[((size_t)b * HPIX + yy * HALO + xx) * 128 + oct * 8] =
                    (ushort8){0, 0, 0, 0, 0, 0, 0, 0};
            }
        }
    }
}

// ---------- 2) s_kernel (routing fused): s[b][p][j] = sum_g probs[b,g,p] * r[b,g*8+j] ----------
__global__ __launch_bounds__(256) void s_kernel(const float* __restrict__ Alpha,
                                                const int* __restrict__ mask,
                                                const float* __restrict__ xse,
                                                const float* __restrict__ rw,
                                                const float* __restrict__ rb,
                                                const int* __restrict__ use_alpha,
                                                float* __restrict__ Sws) {
    const int b = blockIdx.y;
    const int t = threadIdx.x;
    const int p = blockIdx.x * 256 + t;
    __shared__ float xs[IN_C];
    __shared__ float rsh[64];
    if (t < IN_C) xs[t] = xse[b * IN_C + t];
    __syncthreads();
    if (t < 64) {
        float acc = rb[t];
        #pragma unroll 8
        for (int c = 0; c < IN_C; c++) acc += xs[c] * rw[t * IN_C + c];
        rsh[t] = 0.25f / (1.0f + expf(-acc));        // 2*sigmoid/8
    }
    __syncthreads();
    if (p >= PPAD) return;
    float sj[8] = {0, 0, 0, 0, 0, 0, 0, 0};
    if (p < NPIX) {
        float pr[8];
        if (use_alpha[0]) {
            float a[8], m = -1e30f;
            #pragma unroll
            for (int g = 0; g < 8; g++) {
                a[g] = Alpha[((size_t)(b * NG + g)) * NPIX + p];
                m = fmaxf(m, a[g]);
            }
            float sum = 0.f;
            #pragma unroll
            for (int g = 0; g < 8; g++) { pr[g] = expf(a[g] - m); sum += pr[g]; }
            float inv = 1.f / sum;
            #pragma unroll
            for (int g = 0; g < 8; g++) pr[g] *= inv;
        } else {
            int mg = mask[(size_t)b * NPIX + p];
            #pragma unroll
            for (int g = 0; g < 8; g++) pr[g] = (g == mg) ? 1.f : 0.f;
        }
        #pragma unroll
        for (int g = 0; g < 8; g++)
            #pragma unroll
            for (int j = 0; j < 8; j++) sj[j] += pr[g] * rsh[g * 8 + j];
    }
    float* dst = Sws + ((size_t)b * PPAD + p) * 8;
    *(f32x4*)dst = (f32x4){sj[0], sj[1], sj[2], sj[3]};
    *(f32x4*)(dst + 4) = (f32x4){sj[4], sj[5], sj[6], sj[7]};
}

// ---------- 3) main GEMM + blend epilogue (barrier-free, no LDS) ----------
// BM=128 (8 m16), BN=128 px, 256 threads (4 waves: wrow x wcol 2x2).
// Per wave: 4 m16 (tm) x 4 n16 (tn). 36 BK=32 stages, 2-stage ping-pong:
// compute stage s from regs, then reload those regs with stage s+2
// (reload-after-consume; compiler's vmcnt naturally waits for the 8 older
// loads while the 8 newer stay in flight). A-frag: lane (lq,lr) reads 16B at
// Apack + st*512 + m16*18432 + ln*8. B-frag: lane reads 16B at
// Xt[b] + ((kh*58+kw)*128 + c0) + (y*58+x)*128 + lq*8 -- identical data the
// old LDS path delivered (verified swizzle algebra: q = jj ^ swz(row) = lq).
__global__ __launch_bounds__(256) void gemm_kernel(const unsigned short* __restrict__ Apack,
                                                   const unsigned short* __restrict__ Xt,
                                                   const float* __restrict__ Sws,
                                                   const float* __restrict__ bias,
                                                   float* __restrict__ out) {
    const int tid = threadIdx.x;
    const int wv = tid >> 6, ln = tid & 63;
    const int lq = ln >> 4, lr = ln & 15;
    const int wrow = wv >> 1, wcol = wv & 1;

    const int lid = blockIdx.x;            // 0..1599
    const int b   = lid & 7;               // XCD = b
    const int sl  = lid >> 3;              // 0..199
    const int mt  = sl & 7;                // 8 M-tiles of 128 rows
    const int nt  = sl >> 3;               // 0..24

    f32x4 acc[4][4];
    #pragma unroll
    for (int i = 0; i < 4; i++)
        #pragma unroll
        for (int j = 0; j < 4; j++) acc[i][j] = (f32x4){0.f, 0.f, 0.f, 0.f};

    // per-lane A offsets (shorts): m16 = mt*8 + wrow*4 + tm
    int aoff[4];
    #pragma unroll
    for (int tm = 0; tm < 4; tm++) {
        const int m16 = mt * 8 + wrow * 4 + tm;
        aoff[tm] = m16 * 18432 + ln * 8;             // 18432 = 36 stages * 512
    }
    // per-lane B offsets (shorts): pixel p = nt*128 + wcol*64 + tn*16 + lr
    int boff[4];
    #pragma unroll
    for (int tn = 0; tn < 4; tn++) {
        const int p = min(nt * 128 + wcol * 64 + tn * 16 + lr, NPIX - 1);
        const int y = p / WWID, x = p - y * WWID;
        boff[tn] = (y * HALO + x) * 128 + lq * 8;
    }
    const unsigned short* XtB = Xt + (size_t)b * HPIX * 128;

#define LOADST(Ad, Bd, st_) {                                              \
        const int s_ = (st_) >> 2;                                         \
        const int kh_ = s_ / 3, kw_ = s_ - 3 * kh_;                        \
        const int sB_ = (kh_ * HALO + kw_) * 128 + ((st_) & 3) * 32;       \
        const int sA_ = (st_) * 512;                                       \
        _Pragma("unroll")                                                  \
        for (int tm_ = 0; tm_ < 4; tm_++)                                  \
            Ad[tm_] = *(const short8*)(Apack + sA_ + aoff[tm_]);           \
        _Pragma("unroll")                                                  \
        for (int tn_ = 0; tn_ < 4; tn_++)                                  \
            Bd[tn_] = *(const short8*)(XtB + sB_ + boff[tn_]);             \
    }

    short8 A0[4], B0[4], A1[4], B1[4];
    LOADST(A0, B0, 0);
    LOADST(A1, B1, 1);

    #pragma unroll 1
    for (int it = 0; it < 18; it++) {
        const int st2 = it * 2 + 2, st3 = it * 2 + 3;
        // ---- even stage 2it: regs A0/B0 ----
        #pragma unroll
        for (int tm = 0; tm < 4; tm++)
            #pragma unroll
            for (int tn = 0; tn < 4; tn++)
                acc[tm][tn] = __builtin_amdgcn_mfma_f32_16x16x32_bf16(
                    A0[tm], B0[tn], acc[tm][tn], 0, 0, 0);
        if (it < 17) LOADST(A0, B0, st2);            // reload after consume
        // ---- odd stage 2it+1: regs A1/B1 ----
        #pragma unroll
        for (int tm = 0; tm < 4; tm++)
            #pragma unroll
            for (int tn = 0; tn < 4; tn++)
                acc[tm][tn] = __builtin_amdgcn_mfma_f32_16x16x32_bf16(
                    A1[tm], B1[tn], acc[tm][tn], 0, 0, 0);
        if (it < 17) LOADST(A1, B1, st3);
    }
#undef LOADST

    // epilogue: rows m -> j = (lq&1)*4+reg, o_off = lq>>1
    const int j0 = (lq & 1) * 4;
    const int oo = lq >> 1;
    #pragma unroll
    for (int tm = 0; tm < 4; tm++) {
        const int o = mt * 16 + wrow * 8 + tm * 2 + oo;
        const float bo = bias[o];
        #pragma unroll
        for (int tn = 0; tn < 4; tn++) {
            const int p = nt * 128 + wcol * 64 + tn * 16 + lr;
            const f32x4 sv = *(const f32x4*)&Sws[((size_t)b * PPAD + p) * 8 + j0];
            const f32x4 a = acc[tm][tn];
            float part = a.x * sv.x + a.y * sv.y + a.z * sv.z + a.w * sv.w;
            float tot = part + __shfl_xor(part, 16);
            if ((lq & 1) == 0 && p < NPIX)
                out[((size_t)b * OUT_C + o) * NPIX + p] = tot + bo;
        }
    }
}

extern "C" void kernel_launch(void* const* d_in, const int* in_sizes, int n_in,
                              void* d_out, int out_size, void* d_ws, size_t ws_size,
                              hipStream_t stream) {
    const float* inputs = (const float*)d_in[0];
    const int*   mask   = (const int*)d_in[1];
    const float* Alpha  = (const float*)d_in[2];
    const float* wtmpl  = (const float*)d_in[3];
    const float* rw     = (const float*)d_in[4];
    const float* rb     = (const float*)d_in[5];
    const float* bias   = (const float*)d_in[6];
    const int*   ua     = (const int*)d_in[7];
    float* out = (float*)d_out;

    char* ws = (char*)d_ws;
    unsigned short* Xt  = (unsigned short*)ws;                  // 8*3364*128*2 = 6,889,472
    unsigned short* Apk = (unsigned short*)(ws + 6889472);      // 1024*1152*2  = 2,359,296
    float*          Sws = (float*)(ws + 9248768);               // 8*3200*8*4   =   819,200
    float*          xse = (float*)(ws + 10067968);              // 1024*4

    prep_kernel<<<1376, 256, 0, stream>>>(inputs, wtmpl, xse, Apk, Xt);
    s_kernel<<<dim3(13, NB), 256, 0, stream>>>(Alpha, mask, xse, rw, rb, ua, Sws);
    gemm_kernel<<<1600, 256, 0, stream>>>(Apk, Xt, Sws, bias, out);
}

// Round 7
// 171.839 us; speedup vs baseline: 1.3695x; 1.3695x over previous
//
#include <hip/hip_runtime.h>
#include <stdint.h>

#define IN_C   128
#define OUT_C  128
#define KTOT   1152      // IN_C*3*3
#define NG     8
#define NW     8
#define NB     8
#define HH     56
#define WWID   56
#define NPIX   3136
#define PPAD   3200
#define MTOT   1024      // OUT_C*NW
#define HALO   58        // 56 + zero border on each side
#define HPIX   (HALO*HALO)   // 3364

// R7: R4's proven staging (cp16 -> 4x8KB LDS buffers, XOR swizzle, 1 barrier
// per 2 stages) + mfma_f32_32x32x16_bf16. 32x32 doubles FLOP per fragment
// register: B ds_read_b128 per FLOP halves (86k->43k cy/CU), A L2 traffic
// halves, MFMA pipe 4060 vs 3378 FLOP/cy. R4's serial model (MFMA 70k +
// ds_read 86k + conflicts 29k = 185k cy/CU = measured 190k) predicts
// ~114k cy = 48-55us. Apack repacked (prep) to 32x32 fragment-linear:
// lane l&31 = row, k = (l>>5)*8+e (same contiguous-8 convention the working
// 16x16x32 path validates). C/D: col=lane&31, row=(reg&3)+8*(reg>>2)+4*(l>>5).
// B LDS read: octet q = kh*2+hi at slot row*4 + (q ^ swz(row)) -- staging
// swizzle UNCHANGED, balanced 8 lanes/bank-group. R6 lesson: B must stay on
// the coalesced cp16 path. R2/R5 lesson: no launch_bounds register cap.

typedef __attribute__((ext_vector_type(8))) short short8;
typedef __attribute__((ext_vector_type(8))) unsigned short ushort8;
typedef __attribute__((ext_vector_type(4))) float f32x4;
typedef __attribute__((ext_vector_type(16))) float f32x16;

__device__ __forceinline__ unsigned short f2bf(float f) {
    unsigned u = __float_as_uint(f);
    u += 0x7FFF + ((u >> 16) & 1);          // round-to-nearest-even
    return (unsigned short)(u >> 16);
}

__device__ __forceinline__ void cp16(const unsigned short* g, unsigned short* l) {
    __builtin_amdgcn_global_load_lds(
        (const __attribute__((address_space(1))) unsigned int*)g,
        (__attribute__((address_space(3))) unsigned int*)l,
        16, 0, 0);
}

// ---------- 1) fused prep: gap (0..1023) | tconv/pack (1024..1151) | transpose (1152..1375) ----------
__global__ __launch_bounds__(256) void prep_kernel(const float* __restrict__ in,
                                                   const float* __restrict__ T,
                                                   float* __restrict__ xse,
                                                   unsigned short* __restrict__ Apack,
                                                   unsigned short* __restrict__ Xt) {
    __shared__ __align__(16) unsigned char smem[32768];   // 32 KB
    const int blk = blockIdx.x;
    const int t = threadIdx.x;

    if (blk < 1024) {
        // ---- global average pool: xse[b,c] ----
        const float* src = in + (size_t)blk * NPIX;
        float s = 0.f;
        for (int i = t; i < NPIX / 4; i += 256) {
            float4 v = ((const float4*)src)[i];
            s += v.x + v.y + v.z + v.w;
        }
        #pragma unroll
        for (int off = 32; off; off >>= 1) s += __shfl_down(s, off);
        float* ws4 = (float*)smem;
        if ((t & 63) == 0) ws4[t >> 6] = s;
        __syncthreads();
        if (t == 0)
            xse[blk] = (ws4[0] + ws4[1] + ws4[2] + ws4[3]) * (1.0f / (float)NPIX);
        return;
    }
    if (blk < 1152) {
        // ---- tconv+pack: block per o. T[o][k][j] slab -> bf16 LDS (18 KB) ->
        //      32x32 fragment-linear Apack[m32][st][kh][lane][8e]:
        //      m32 = o>>2, lane = hi*32 + (o&3)*8 + j, k = st*32+kh*16+hi*8+e.
        unsigned short* lh = (unsigned short*)smem;  // 9216 bf16 = 18 KB
        const int o = blk - 1024;
        const float* To = T + (size_t)o * 9216;
        #pragma unroll
        for (int it = 0; it < 9; it++) {
            const int f = it * 256 + t;              // 0..2303 float4 units
            const float4 v = ((const float4*)To)[f];
            ushort4 h;
            h.x = f2bf(v.x); h.y = f2bf(v.y); h.z = f2bf(v.z); h.w = f2bf(v.w);
            *(ushort4*)&lh[f * 4] = h;
        }
        __syncthreads();
        #pragma unroll
        for (int it = 0; it < 5; it++) {
            const int ch = it * 256 + t;             // 0..1151: ch = kc*8 + j
            if (ch < 1152) {
                const int j = ch & 7, kc = ch >> 3;  // kc = k-octet 0..143
                const int s = kc >> 4, c0 = (kc & 15) << 3;
                const int stg = s * 4 + ((c0 >> 5) & 3);   // BK=32 stage 0..35
                const int khb = (c0 >> 4) & 1;             // k-half within stage
                const int hib = (c0 >> 3) & 1;             // lane>>5 half
                ushort8 v;
                #pragma unroll
                for (int i = 0; i < 8; i++)
                    v[i] = lh[((c0 + i) * 9 + s) * 8 + j];
                const size_t off = ((((size_t)(o >> 2) * 36 + stg) * 2 + khb) * 64
                                    + hib * 32 + (o & 3) * 8 + j) * 8;
                *(ushort8*)&Apack[off] = v;
            }
        }
        return;
    }
    // ---- transpose: in[b][c][y][x] fp32 -> Xt[b][(y+1)*58+(x+1)][c] bf16, zero halo ----
    unsigned short* tile = (unsigned short*)smem;    // 32 KB, [c][pix 0..112)
    const int idx = blk - 1152;                      // 0..223
    const int yt = idx % 28;
    const int b  = idx / 28;
    const int y0 = yt * 2;

    #pragma unroll
    for (int it = 0; it < 14; it++) {
        const int f = it * 256 + t;
        const int c = f / 28;
        const int rem = f - c * 28;
        const int y = rem / 14;
        const int x4 = rem - y * 14;
        const float4 v = *(const float4*)(in + ((size_t)(b * IN_C + c)) * NPIX
                                          + (y0 + y) * WWID + x4 * 4);
        unsigned short bf0 = f2bf(v.x), bf1 = f2bf(v.y), bf2 = f2bf(v.z), bf3 = f2bf(v.w);
        const int ppb = (y * WWID + x4 * 4) ^ (((c >> 3) & 15) << 2);
        uint2 pk;
        pk.x = (unsigned)bf0 | ((unsigned)bf1 << 16);
        pk.y = (unsigned)bf2 | ((unsigned)bf3 << 16);
        *(uint2*)&tile[c * 128 + ppb] = pk;
    }
    __syncthreads();

    #pragma unroll
    for (int it = 0; it < 7; it++) {
        const int ch = it * 256 + t;
        const int oct = ch & 15;
        const int pp = ch >> 4;
        const int sw = oct << 2;
        ushort8 v;
        #pragma unroll
        for (int i = 0; i < 8; i++)
            v[i] = tile[(oct * 8 + i) * 128 + (pp ^ sw)];
        const int y2 = (pp >= WWID) ? 1 : 0;
        const int xg = pp - y2 * WWID;
        const size_t hp = (size_t)b * HPIX + (y0 + y2 + 1) * HALO + (xg + 1);
        *(ushort8*)&Xt[hp * 128 + oct * 8] = v;
    }

    if (t < 64) {   // halo columns xx=0,57 for this block's two rows
        const int pi = t >> 4, oct = t & 15;
        const int yy = y0 + 1 + (pi >> 1);
        const int xx = (pi & 1) * 57;
        *(ushort8*)&Xt[((size_t)b * HPIX + yy * HALO + xx) * 128 + oct * 8] =
            (ushort8){0, 0, 0, 0, 0, 0, 0, 0};
    }
    if (yt == 0 || yt == 27) {   // halo rows yy=0 / 57
        const int yy = (yt == 0) ? 0 : 57;
        #pragma unroll
        for (int it = 0; it < 4; it++) {
            const int ch = it * 256 + t;
            if (ch < 928) {
                const int xx = ch >> 4, oct = ch & 15;
                *(ushort8*)&Xt[((size_t)b * HPIX + yy * HALO + xx) * 128 + oct * 8] =
                    (ushort8){0, 0, 0, 0, 0, 0, 0, 0};
            }
        }
    }
}

// ---------- 2) s_kernel (routing fused): s[b][p][j] = sum_g probs[b,g,p] * r[b,g*8+j] ----------
__global__ __launch_bounds__(256) void s_kernel(const float* __restrict__ Alpha,
                                                const int* __restrict__ mask,
                                                const float* __restrict__ xse,
                                                const float* __restrict__ rw,
                                                const float* __restrict__ rb,
                                                const int* __restrict__ use_alpha,
                                                float* __restrict__ Sws) {
    const int b = blockIdx.y;
    const int t = threadIdx.x;
    const int p = blockIdx.x * 256 + t;
    __shared__ float xs[IN_C];
    __shared__ float rsh[64];
    if (t < IN_C) xs[t] = xse[b * IN_C + t];
    __syncthreads();
    if (t < 64) {
        float acc = rb[t];
        #pragma unroll 8
        for (int c = 0; c < IN_C; c++) acc += xs[c] * rw[t * IN_C + c];
        rsh[t] = 0.25f / (1.0f + expf(-acc));        // 2*sigmoid/8
    }
    __syncthreads();
    if (p >= PPAD) return;
    float sj[8] = {0, 0, 0, 0, 0, 0, 0, 0};
    if (p < NPIX) {
        float pr[8];
        if (use_alpha[0]) {
            float a[8], m = -1e30f;
            #pragma unroll
            for (int g = 0; g < 8; g++) {
                a[g] = Alpha[((size_t)(b * NG + g)) * NPIX + p];
                m = fmaxf(m, a[g]);
            }
            float sum = 0.f;
            #pragma unroll
            for (int g = 0; g < 8; g++) { pr[g] = expf(a[g] - m); sum += pr[g]; }
            float inv = 1.f / sum;
            #pragma unroll
            for (int g = 0; g < 8; g++) pr[g] *= inv;
        } else {
            int mg = mask[(size_t)b * NPIX + p];
            #pragma unroll
            for (int g = 0; g < 8; g++) pr[g] = (g == mg) ? 1.f : 0.f;
        }
        #pragma unroll
        for (int g = 0; g < 8; g++)
            #pragma unroll
            for (int j = 0; j < 8; j++) sj[j] += pr[g] * rsh[g * 8 + j];
    }
    float* dst = Sws + ((size_t)b * PPAD + p) * 8;
    *(f32x4*)dst = (f32x4){sj[0], sj[1], sj[2], sj[3]};
    *(f32x4*)(dst + 4) = (f32x4){sj[4], sj[5], sj[6], sj[7]};
}

// ---------- 3) main GEMM + blend epilogue (32x32x16 MFMA) ----------
// BM=128 (4 m32), BN=128 px (4 n32), 256 threads (4 waves 2x2).
// Per wave: 2 m32 (tm) x 2 n32 (tn), acc f32x16[2][2]. 36 BK=32 stages in
// 18 pairs: 4 x 8KB B-buffers (cp16, swizzle, addresses IDENTICAL to R4),
// one barrier per pair, B prefetch pair p+1 at top of p, A reload-after-
// consume (A0/A1 stage ping-pong, 8 short8 = 32 VGPR). Grid 1600.
__global__ __launch_bounds__(256) void gemm_kernel(const unsigned short* __restrict__ Apack,
                                                   const unsigned short* __restrict__ Xt,
                                                   const float* __restrict__ Sws,
                                                   const float* __restrict__ bias,
                                                   float* __restrict__ out) {
    __shared__ __align__(16) unsigned short Bsh[4][512 * 8];   // 4 x 8 KB
    const int tid = threadIdx.x;
    const int wv = tid >> 6, ln = tid & 63;
    const int u  = ln & 31, hi = ln >> 5;
    const int wrow = wv >> 1, wcol = wv & 1;

    const int lid = blockIdx.x;            // 0..1599
    const int b   = lid & 7;               // XCD = b
    const int sl  = lid >> 3;              // 0..199
    const int mt  = sl & 7;                // 8 M-tiles of 128 rows
    const int nt  = sl >> 3;               // 0..24

    f32x16 acc[2][2];
    #pragma unroll
    for (int i = 0; i < 2; i++)
        #pragma unroll
        for (int j = 0; j < 2; j++)
            #pragma unroll
            for (int e = 0; e < 16; e++) acc[i][j][e] = 0.f;

    // B staging (UNCHANGED from R4): chunk (r, js) holds octet q = js ^ swz(r)
    const int js = tid & 3;
    const int r0 = tid >> 2,  q0 = js ^ (r0 & 3) ^ ((r0 >> 2) & 3);
    const int r1 = r0 + 64,   q1 = js ^ (r1 & 3) ^ ((r1 >> 2) & 3);
    const int p0 = min(nt * 128 + r0, NPIX - 1);
    const int p1 = min(nt * 128 + r1, NPIX - 1);
    const int y0p = p0 / WWID, x0p = p0 - y0p * WWID;
    const int y1p = p1 / WWID, x1p = p1 - y1p * WWID;
    const unsigned short* gb0 = Xt + ((size_t)b * HPIX + y0p * HALO + x0p) * 128 + q0 * 8;
    const unsigned short* gb1 = Xt + ((size_t)b * HPIX + y1p * HALO + x1p) * 128 + q1 * 8;
    unsigned short* lbA[4];   // per-buffer LDS target for chunk0 (chunk1 = +256*8)
    #pragma unroll
    for (int i = 0; i < 4; i++) lbA[i] = &Bsh[i][(wv * 64) * 8];

    // A fragment-linear bases: m32 = mt*4 + wrow*2 + tm; 36864 shorts per m32
    const unsigned short* gawB[2];
    #pragma unroll
    for (int tm = 0; tm < 2; tm++) {
        const int m32 = mt * 4 + wrow * 2 + tm;
        gawB[tm] = Apack + (size_t)m32 * 36864 + ln * 8;
    }

    // B LDS read offsets (shorts): octet q = kh*2+hi of row = wcol*64+tn*32+u,
    // slot = row*4 + (q ^ (u&3) ^ ((u>>2)&3))
    const int jbase = hi ^ (u & 3) ^ ((u >> 2) & 3);
    int boffL[2][2];
    #pragma unroll
    for (int tn = 0; tn < 2; tn++)
        #pragma unroll
        for (int kh = 0; kh < 2; kh++) {
            const int row = wcol * 64 + tn * 32 + u;
            boffL[tn][kh] = (row * 4 + (jbase ^ (kh << 1))) * 8;
        }

#define ALOAD(Ad, st_) { _Pragma("unroll")                                    \
        for (int tm_ = 0; tm_ < 2; tm_++) { _Pragma("unroll")                 \
            for (int kh_ = 0; kh_ < 2; kh_++)                                 \
                Ad[tm_][kh_] = *(const short8*)(gawB[tm_] + (st_) * 1024 + kh_ * 512); } }

#define STAGE(Ad, buf_) {                                                     \
        short8 b0 = *(const short8*)&Bsh[buf_][boffL[0][0]];                  \
        short8 b1 = *(const short8*)&Bsh[buf_][boffL[1][0]];                  \
        acc[0][0] = __builtin_amdgcn_mfma_f32_32x32x16_bf16(Ad[0][0], b0, acc[0][0], 0, 0, 0); \
        acc[0][1] = __builtin_amdgcn_mfma_f32_32x32x16_bf16(Ad[0][0], b1, acc[0][1], 0, 0, 0); \
        acc[1][0] = __builtin_amdgcn_mfma_f32_32x32x16_bf16(Ad[1][0], b0, acc[1][0], 0, 0, 0); \
        acc[1][1] = __builtin_amdgcn_mfma_f32_32x32x16_bf16(Ad[1][0], b1, acc[1][1], 0, 0, 0); \
        b0 = *(const short8*)&Bsh[buf_][boffL[0][1]];                         \
        b1 = *(const short8*)&Bsh[buf_][boffL[1][1]];                         \
        acc[0][0] = __builtin_amdgcn_mfma_f32_32x32x16_bf16(Ad[0][1], b0, acc[0][0], 0, 0, 0); \
        acc[0][1] = __builtin_amdgcn_mfma_f32_32x32x16_bf16(Ad[0][1], b1, acc[0][1], 0, 0, 0); \
        acc[1][0] = __builtin_amdgcn_mfma_f32_32x32x16_bf16(Ad[1][1], b0, acc[1][0], 0, 0, 0); \
        acc[1][1] = __builtin_amdgcn_mfma_f32_32x32x16_bf16(Ad[1][1], b1, acc[1][1], 0, 0, 0); }

    // prologue: tiles 0,1 -> buf0,buf1 (stage1 offB = 32); A0/A1 = stages 0,1
    cp16(gb0, lbA[0]); cp16(gb1, lbA[0] + 256 * 8);
    cp16(gb0 + 32, lbA[1]); cp16(gb1 + 32, lbA[1] + 256 * 8);
    short8 A0[2][2], A1[2][2];
    ALOAD(A0, 0);
    ALOAD(A1, 1);

    #pragma unroll 1
    for (int pr = 0; pr < 18; pr++) {
        __syncthreads();                   // tiles 2pr,2pr+1 + A0,A1 ready
        const int st2 = pr * 2 + 2, st3 = pr * 2 + 3;
        if (pr < 17) {                     // prefetch pair pr+1 B tiles
            const int nk2 = st2 * 32, s2 = nk2 >> 7;
            const int kh2 = s2 / 3, kw2 = s2 - 3 * kh2;
            const int off2 = (kh2 * HALO + kw2) * 128 + (nk2 & 127);
            const int nk3 = st3 * 32, s3 = nk3 >> 7;
            const int kh3 = s3 / 3, kw3 = s3 - 3 * kh3;
            const int off3 = (kh3 * HALO + kw3) * 128 + (nk3 & 127);
            unsigned short* d2 = lbA[st2 & 3];
            unsigned short* d3 = lbA[st3 & 3];
            cp16(gb0 + off2, d2); cp16(gb1 + off2, d2 + 256 * 8);
            cp16(gb0 + off3, d3); cp16(gb1 + off3, d3 + 256 * 8);
        }
        const int bufa = (pr & 1) * 2;
        STAGE(A0, bufa);                   // stage 2pr
        if (pr < 17) ALOAD(A0, st2);       // reload after consume
        STAGE(A1, bufa + 1);               // stage 2pr+1
        if (pr < 17) ALOAD(A1, st3);
    }
#undef STAGE
#undef ALOAD

    // epilogue: C elem (q,d): global row m = m32*32 + 8q + 4hi + d ->
    // o = m32*4 + q, j = 4hi + d. Sum over j: dot with Sws[...][4hi..4hi+3],
    // then cross-half add via shfl_xor(32). col p = ... + u.
    const int j0 = hi * 4;
    #pragma unroll
    for (int tm = 0; tm < 2; tm++) {
        const int m32 = mt * 4 + wrow * 2 + tm;
        #pragma unroll
        for (int tn = 0; tn < 2; tn++) {
            const int p = nt * 128 + wcol * 64 + tn * 32 + u;
            const int pS = min(p, NPIX - 1);
            const f32x4 sv = *(const f32x4*)&Sws[((size_t)b * PPAD + pS) * 8 + j0];
            const f32x16 a = acc[tm][tn];
            #pragma unroll
            for (int q = 0; q < 4; q++) {
                float part = a[q * 4 + 0] * sv.x + a[q * 4 + 1] * sv.y
                           + a[q * 4 + 2] * sv.z + a[q * 4 + 3] * sv.w;
                float tot = part + __shfl_xor(part, 32);
                const int o = m32 * 4 + q;
                if (hi == 0 && p < NPIX)
                    out[((size_t)(b * OUT_C + o)) * NPIX + p] = tot + bias[o];
            }
        }
    }
}

extern "C" void kernel_launch(void* const* d_in, const int* in_sizes, int n_in,
                              void* d_out, int out_size, void* d_ws, size_t ws_size,
                              hipStream_t stream) {
    const float* inputs = (const float*)d_in[0];
    const int*   mask   = (const int*)d_in[1];
    const float* Alpha  = (const float*)d_in[2];
    const float* wtmpl  = (const float*)d_in[3];
    const float* rw     = (const float*)d_in[4];
    const float* rb     = (const float*)d_in[5];
    const float* bias   = (const float*)d_in[6];
    const int*   ua     = (const int*)d_in[7];
    float* out = (float*)d_out;

    char* ws = (char*)d_ws;
    unsigned short* Xt  = (unsigned short*)ws;                  // 8*3364*128*2 = 6,889,472
    unsigned short* Apk = (unsigned short*)(ws + 6889472);      // 1024*1152*2  = 2,359,296
    float*          Sws = (float*)(ws + 9248768);               // 8*3200*8*4   =   819,200
    float*          xse = (float*)(ws + 10067968);              // 1024*4

    prep_kernel<<<1376, 256, 0, stream>>>(inputs, wtmpl, xse, Apk, Xt);
    s_kernel<<<dim3(13, NB), 256, 0, stream>>>(Alpha, mask, xse, rw, rb, ua, Sws);
    gemm_kernel<<<1600, 256, 0, stream>>>(Apk, Xt, Sws, bias, out);
}